// Round 1
// baseline (427.018 us; speedup 1.0000x reference)
//
#include <hip/hip_runtime.h>
#include <cstdint>
#include <cfloat>

// Problem constants (B=64, H=12, P=197, D=64)
#define NK 10
constexpr int Pp   = 197;
constexpr int Dd   = 64;
constexpr int ROWS = 64 * 12 * 197;      // 151296
constexpr int BLK  = 256;                // threads per block
constexpr int RPB  = 256;                // rows per block (thread-per-row)
constexpr int NBLK = ROWS / RPB;         // 591 (exact)
constexpr int CH   = 32;                 // staging chunk width (cols)
constexpr int NFULL = Pp / CH;           // 6 full chunks
constexpr int TAIL  = Pp - NFULL * CH;   // 5
constexpr float INV_N = 1.0f / 9682944.0f;   // 1/(ROWS*D)

__device__ __forceinline__ uint32_t fbits(float x) { return __float_as_uint(x); }
__device__ __forceinline__ float    bfl(uint32_t u) { return __uint_as_float(u); }

// Branchless sorted-insert of one packed value into ascending a[0..9].
// a[s] = max(a[s], min(x, a[s+1])) reads the OLD a[s+1] (s ascending) — correct.
template <int CW>
__device__ __forceinline__ void consume_chunk(const float (*tile)[CH + 1], int t,
                                              float a[NK]) {
#pragma unroll
  for (int j = 0; j < CW; ++j) {
    float x = tile[t][j];
#pragma unroll
    for (int s = 0; s < NK - 1; ++s) a[s] = fmaxf(a[s], fminf(x, a[s + 1]));
    a[NK - 1] = fmaxf(a[NK - 1], x);
  }
}

// Selection for one att tensor: fills wpk[row][k] = weight with column idx
// packed into the low 8 mantissa bits (rel. perturbation 2^-16, negligible
// for the scalar-mean output).
__device__ __forceinline__ void select_rows(const float* __restrict__ A,
                                            float (*tile)[CH + 1],
                                            float (*wpk)[NK], int t,
                                            int blockRow0) {
  float a[NK];
#pragma unroll
  for (int k = 0; k < NK; ++k) a[k] = -FLT_MAX;

  const float* slab = A + (size_t)blockRow0 * Pp;

  for (int c = 0; c < NFULL; ++c) {
    __syncthreads();  // previous tile fully consumed
    const float* cbase = slab + c * CH;
#pragma unroll 8
    for (int e = t; e < RPB * CH; e += BLK) {
      int r = e >> 5, j = e & 31;
      float x = cbase[r * Pp + j];
      uint32_t u = (fbits(x) & 0xFFFFFF00u) | (uint32_t)(c * CH + j);
      tile[r][j] = bfl(u);
    }
    __syncthreads();
    consume_chunk<CH>(tile, t, a);
  }
  // tail chunk (5 cols)
  __syncthreads();
  {
    const float* cbase = slab + NFULL * CH;
    for (int e = t; e < RPB * TAIL; e += BLK) {
      int r = e / TAIL, j = e % TAIL;  // constant divisor -> magic mul
      float x = cbase[r * Pp + j];
      uint32_t u = (fbits(x) & 0xFFFFFF00u) | (uint32_t)(NFULL * CH + j);
      tile[r][j] = bfl(u);
    }
  }
  __syncthreads();
  consume_chunk<TAIL>(tile, t, a);

  // softmax over the top-10 (full-row Z cancels against the renorm)
  float mx = a[NK - 1];
  float e[NK], s = 0.f;
#pragma unroll
  for (int k = 0; k < NK; ++k) {
    e[k] = __expf(a[k] - mx);
    s += e[k];
  }
  float inv = 1.0f / s;
#pragma unroll
  for (int k = 0; k < NK; ++k) {
    float w = e[k] * inv;  // w >= ~1e-6 always -> normal float, packing safe
    uint32_t wb = (fbits(w) & 0xFFFFFF00u) | (fbits(a[k]) & 0xFFu);
    wpk[t][k] = bfl(wb);
  }
}

__global__ __launch_bounds__(BLK) void topk_mse_kernel(
    const float* __restrict__ att_s, const float* __restrict__ att_t,
    const float* __restrict__ v_s, const float* __restrict__ v_t,
    float* __restrict__ out) {
  __shared__ float tile[RPB][CH + 1];   // 33792 B
  __shared__ float wpk[2][RPB][NK];     // 20480 B
  __shared__ float red[BLK / 64];

  const int t = threadIdx.x;
  const int blockRow0 = blockIdx.x * RPB;

  select_rows(att_s, tile, wpk[0], t, blockRow0);
  select_rows(att_t, tile, wpk[1], t, blockRow0);
  __syncthreads();

  // Phase B: wave-per-row gather, lane = d (D==64==wave size). Coalesced
  // 256B v loads; w reads are uniform-address LDS broadcasts.
  const int wv = t >> 6, l = t & 63;
  float accsum = 0.f;
  for (int i = 0; i < 64; ++i) {
    int rl = (wv << 6) | i;
    int rg = blockRow0 + rl;
    int bh = rg / Pp;  // constant divisor -> magic mul
    const float* vsb = v_s + (size_t)bh * (Pp * Dd);
    const float* vtb = v_t + (size_t)bh * (Pp * Dd);
    float acc = 0.f;
#pragma unroll
    for (int k = 0; k < NK; ++k) {
      float w = wpk[0][rl][k];
      int idx = (int)(fbits(w) & 0xFFu);
      acc = fmaf(w, vsb[idx * Dd + l], acc);
    }
#pragma unroll
    for (int k = 0; k < NK; ++k) {
      float w = wpk[1][rl][k];
      int idx = (int)(fbits(w) & 0xFFu);
      acc = fmaf(-w, vtb[idx * Dd + l], acc);
    }
    accsum = fmaf(acc, acc, accsum);
  }

  // reduce: wave butterfly -> LDS -> one atomic per block
#pragma unroll
  for (int off = 32; off > 0; off >>= 1) accsum += __shfl_xor(accsum, off, 64);
  if (l == 0) red[wv] = accsum;
  __syncthreads();
  if (t == 0) {
    float tot = (red[0] + red[1]) + (red[2] + red[3]);
    atomicAdd(out, tot * INV_N);
  }
}

extern "C" void kernel_launch(void* const* d_in, const int* in_sizes, int n_in,
                              void* d_out, int out_size, void* d_ws,
                              size_t ws_size, hipStream_t stream) {
  const float* att_s = (const float*)d_in[0];
  const float* att_t = (const float*)d_in[1];
  const float* v_s = (const float*)d_in[2];
  const float* v_t = (const float*)d_in[3];
  float* out = (float*)d_out;

  hipMemsetAsync(out, 0, sizeof(float), stream);  // graph-capturable memset node
  topk_mse_kernel<<<NBLK, BLK, 0, stream>>>(att_s, att_t, v_s, v_t, out);
}

// Round 2
// 385.577 us; speedup vs baseline: 1.1075x; 1.1075x over previous
//
#include <hip/hip_runtime.h>
#include <cstdint>
#include <cfloat>

// Problem constants (B=64, H=12, P=197, D=64)
#define NK 10
constexpr int Pp   = 197;
constexpr int Dd   = 64;
constexpr int ROWS = 64 * 12 * 197;      // 151296
constexpr int BLK  = 256;                // threads per block
constexpr int RPB  = 256;                // rows per block (thread-per-row)
constexpr int NBLK = ROWS / RPB;         // 591 (exact)
constexpr int CH   = 32;                 // staging chunk width (cols)
constexpr int NFULL = Pp / CH;           // 6 full chunks
constexpr int TAIL  = Pp - NFULL * CH;   // 5
constexpr float INV_N = 1.0f / 9682944.0f;   // 1/(ROWS*D)

__device__ __forceinline__ uint32_t fbits(float x) { return __float_as_uint(x); }
__device__ __forceinline__ float    bfl(uint32_t u) { return __uint_as_float(u); }

// Branchless sorted-insert of one packed value into ascending a[0..9].
// a[s] = max(a[s], min(x, a[s+1])) reads OLD a[s+1] (s ascending) — correct.
template <int CW>
__device__ __forceinline__ void consume_chunk(const float* __restrict__ trow,
                                              float a[NK]) {
#pragma unroll
  for (int j = 0; j < CW; ++j) {
    float x = trow[j];
#pragma unroll
    for (int s = 0; s < NK - 1; ++s) a[s] = fmaxf(a[s], fminf(x, a[s + 1]));
    a[NK - 1] = fmaxf(a[NK - 1], x);
  }
}

// Load chunk c of this block's 256-row slab into registers, packing the
// column index into the low 8 mantissa bits (rel. perturbation 2^-16).
// Full chunks: element i lives at row (t>>5)+8i, col (t&31) of the chunk —
// a single base pointer + i*8*Pp stride (keeps live addresses to one pair).
__device__ __forceinline__ void load_chunk_regs(const float* __restrict__ slab,
                                                int c, int t, float pf[CH]) {
  if (c < NFULL) {
    const int r0 = t >> 5, j = t & 31;
    const uint32_t col = (uint32_t)(c * CH + j);
    const float* p = slab + c * CH + r0 * Pp + j;
#pragma unroll
    for (int i = 0; i < CH; ++i) {
      float x = p[i * 8 * Pp];
      pf[i] = bfl((fbits(x) & 0xFFFFFF00u) | col);
    }
  } else {
    const float* cbase = slab + NFULL * CH;
#pragma unroll
    for (int i = 0; i < TAIL; ++i) {
      int e = t + i * BLK;
      int r = e / TAIL, j = e % TAIL;  // constant divisor -> magic mul
      float x = cbase[r * Pp + j];
      pf[i] = bfl((fbits(x) & 0xFFFFFF00u) | (uint32_t)(NFULL * CH + j));
    }
  }
}

__device__ __forceinline__ void store_chunk(float (*tile)[CH + 1], int c, int t,
                                            const float pf[CH]) {
  if (c < NFULL) {
    const int r0 = t >> 5, j = t & 31;
#pragma unroll
    for (int i = 0; i < CH; ++i) tile[r0 + 8 * i][j] = pf[i];
  } else {
#pragma unroll
    for (int i = 0; i < TAIL; ++i) {
      int e = t + i * BLK;
      tile[e / TAIL][e % TAIL] = pf[i];
    }
  }
}

// Selection for one att tensor; results (softmaxed top-10 weight with col idx
// packed in low mantissa byte) land in registers wsel[0..9] of thread t=row.
__device__ __forceinline__ void select_rows(const float* __restrict__ A,
                                            float (*tile)[CH + 1],
                                            float wsel[NK], int t,
                                            int blockRow0) {
  float a[NK];
#pragma unroll
  for (int k = 0; k < NK; ++k) a[k] = -FLT_MAX;

  const float* slab = A + (size_t)blockRow0 * Pp;
  float pf[CH];

  load_chunk_regs(slab, 0, t, pf);
  for (int c = 0; c <= NFULL; ++c) {
    __syncthreads();               // tile from previous chunk fully consumed
    store_chunk(tile, c, t, pf);   // drains vmcnt for this chunk only
    __syncthreads();               // tile ready
    if (c < NFULL) {
      load_chunk_regs(slab, c + 1, t, pf);  // next loads fly during consume
      consume_chunk<CH>(tile[t], a);
    } else {
      consume_chunk<TAIL>(tile[t], a);
    }
  }

  // softmax over the top-10 (full-row Z cancels against the renorm)
  float mx = a[NK - 1];
  float e[NK], s = 0.f;
#pragma unroll
  for (int k = 0; k < NK; ++k) {
    e[k] = __expf(a[k] - mx);
    s += e[k];
  }
  float inv = 1.0f / s;
#pragma unroll
  for (int k = 0; k < NK; ++k) {
    float w = e[k] * inv;  // w >= ~1e-6 -> normal float, packing safe
    wsel[k] = bfl((fbits(w) & 0xFFFFFF00u) | (fbits(a[k]) & 0xFFu));
  }
}

__global__ __launch_bounds__(BLK, 4) void topk_mse_kernel(
    const float* __restrict__ att_s, const float* __restrict__ att_t,
    const float* __restrict__ v_s, const float* __restrict__ v_t,
    float* __restrict__ out) {
  __shared__ float tile[RPB][CH + 1];  // 33792 B (only LDS of consequence)
  __shared__ float red[BLK / 64];

  const int t = threadIdx.x;
  const int blockRow0 = blockIdx.x * RPB;

  float wsel[2][NK];  // packed weights stay in registers
  select_rows(att_s, tile, wsel[0], t, blockRow0);
  select_rows(att_t, tile, wsel[1], t, blockRow0);

  // Phase B: wave-per-row gather, lane = d (D==64==wave). Row wv*64+i's
  // weights live in lane i of THIS wave -> __shfl broadcast, no LDS.
  const int wv = t >> 6, l = t & 63;
  float accsum = 0.f;
  for (int i = 0; i < 64; ++i) {
    int rl = (wv << 6) | i;
    int rg = blockRow0 + rl;
    int bh = rg / Pp;  // constant divisor -> magic mul
    const float* vsb = v_s + (size_t)bh * (Pp * Dd) + l;
    const float* vtb = v_t + (size_t)bh * (Pp * Dd) + l;
    float acc = 0.f;
#pragma unroll
    for (int k = 0; k < NK; ++k) {
      float w = __shfl(wsel[0][k], i, 64);
      int idx = (int)(fbits(w) & 0xFFu);
      acc = fmaf(w, vsb[idx * Dd], acc);
    }
#pragma unroll
    for (int k = 0; k < NK; ++k) {
      float w = __shfl(wsel[1][k], i, 64);
      int idx = (int)(fbits(w) & 0xFFu);
      acc = fmaf(-w, vtb[idx * Dd], acc);
    }
    accsum = fmaf(acc, acc, accsum);
  }

  // reduce: wave butterfly -> LDS -> one atomic per block
#pragma unroll
  for (int off = 32; off > 0; off >>= 1) accsum += __shfl_xor(accsum, off, 64);
  if (l == 0) red[wv] = accsum;
  __syncthreads();
  if (t == 0) {
    float tot = (red[0] + red[1]) + (red[2] + red[3]);
    atomicAdd(out, tot * INV_N);
  }
}

extern "C" void kernel_launch(void* const* d_in, const int* in_sizes, int n_in,
                              void* d_out, int out_size, void* d_ws,
                              size_t ws_size, hipStream_t stream) {
  const float* att_s = (const float*)d_in[0];
  const float* att_t = (const float*)d_in[1];
  const float* v_s = (const float*)d_in[2];
  const float* v_t = (const float*)d_in[3];
  float* out = (float*)d_out;

  hipMemsetAsync(out, 0, sizeof(float), stream);  // graph-capturable node
  topk_mse_kernel<<<NBLK, BLK, 0, stream>>>(att_s, att_t, v_s, v_t, out);
}

// Round 3
// 378.988 us; speedup vs baseline: 1.1267x; 1.0174x over previous
//
#include <hip/hip_runtime.h>
#include <cstdint>
#include <cfloat>

// Problem constants (B=64, H=12, P=197, D=64)
#define NK 10
constexpr int Pp   = 197;
constexpr int Dd   = 64;
constexpr int ROWS = 64 * 12 * 197;      // 151296
constexpr int BLK  = 256;                // selection threads per block
constexpr int RPB  = 256;                // rows per selection block
constexpr int NBLK = ROWS / RPB;         // 591
constexpr int CH   = 32;                 // staging chunk width (cols)
constexpr int NFULL = Pp / CH;           // 6
constexpr int TAIL  = Pp - NFULL * CH;   // 5
constexpr float INV_N = 1.0f / 9682944.0f;   // 1/(ROWS*D)

constexpr int RPB_B = 16;                // rows per gather block (16 waves)
constexpr int NB_B  = ROWS / RPB_B;      // 9456 (exact)

__device__ __forceinline__ uint32_t fbits(float x) { return __float_as_uint(x); }
__device__ __forceinline__ float    bfl(uint32_t u) { return __uint_as_float(u); }

// Branchless sorted-insert into ascending a[0..9].
template <int CW>
__device__ __forceinline__ void consume_chunk(const float* __restrict__ trow,
                                              float a[NK]) {
#pragma unroll
  for (int j = 0; j < CW; ++j) {
    float x = trow[j];
#pragma unroll
    for (int s = 0; s < NK - 1; ++s) a[s] = fmaxf(a[s], fminf(x, a[s + 1]));
    a[NK - 1] = fmaxf(a[NK - 1], x);
  }
}

// Load chunk c into registers, packing the column index into the low 8
// mantissa bits (rel. perturbation 2^-16 — negligible for a scalar mean).
__device__ __forceinline__ void load_chunk_regs(const float* __restrict__ slab,
                                                int c, int t, float pf[CH]) {
  if (c < NFULL) {
    const int r0 = t >> 5, j = t & 31;
    const uint32_t col = (uint32_t)(c * CH + j);
    const float* p = slab + c * CH + r0 * Pp + j;
#pragma unroll
    for (int i = 0; i < CH; ++i) {
      float x = __builtin_nontemporal_load(&p[i * 8 * Pp]);  // att is read-once
      pf[i] = bfl((fbits(x) & 0xFFFFFF00u) | col);
    }
  } else {
    const float* cbase = slab + NFULL * CH;
#pragma unroll
    for (int i = 0; i < TAIL; ++i) {
      int e = t + i * BLK;
      int r = e / TAIL, j = e % TAIL;
      float x = __builtin_nontemporal_load(&cbase[r * Pp + j]);
      pf[i] = bfl((fbits(x) & 0xFFFFFF00u) | (uint32_t)(NFULL * CH + j));
    }
  }
}

__device__ __forceinline__ void store_chunk(float (*tile)[CH + 1], int c, int t,
                                            const float pf[CH]) {
  if (c < NFULL) {
    const int r0 = t >> 5, j = t & 31;
#pragma unroll
    for (int i = 0; i < CH; ++i) tile[r0 + 8 * i][j] = pf[i];
  } else {
#pragma unroll
    for (int i = 0; i < TAIL; ++i) {
      int e = t + i * BLK;
      tile[e / TAIL][e % TAIL] = pf[i];
    }
  }
}

// Kernel A: one block = one 256-row slab of ONE tensor (grid = 2*NBLK).
// Emits packed softmaxed top-10 weights (idx in low mantissa byte) to wpk.
__global__ __launch_bounds__(BLK, 4) void select_kernel(
    const float* __restrict__ att_s, const float* __restrict__ att_t,
    float* __restrict__ wpk /* [2][ROWS][NK] */) {
  __shared__ float tile[RPB][CH + 1];  // 33792 B

  const int t = threadIdx.x;
  const int bi = blockIdx.x;
  const int tensor = (bi >= NBLK) ? 1 : 0;
  const int slab = bi - tensor * NBLK;
  const float* A = tensor ? att_t : att_s;
  const int blockRow0 = slab * RPB;

  float a[NK];
#pragma unroll
  for (int k = 0; k < NK; ++k) a[k] = -FLT_MAX;

  const float* slabp = A + (size_t)blockRow0 * Pp;
  float pf[CH];

  load_chunk_regs(slabp, 0, t, pf);
  for (int c = 0; c <= NFULL; ++c) {
    __syncthreads();               // previous tile fully consumed
    store_chunk(tile, c, t, pf);
    __syncthreads();               // tile ready
    if (c < NFULL) {
      load_chunk_regs(slabp, c + 1, t, pf);  // next chunk flies during consume
      consume_chunk<CH>(tile[t], a);
    } else {
      consume_chunk<TAIL>(tile[t], a);
    }
  }

  // softmax over the top-10 (full-row Z cancels against the renorm)
  float mx = a[NK - 1];
  float e[NK], s = 0.f;
#pragma unroll
  for (int k = 0; k < NK; ++k) { e[k] = __expf(a[k] - mx); s += e[k]; }
  float inv = 1.0f / s;

  // stage packed weights in (now free) tile, then coalesced store
  __syncthreads();
  float* flat = &tile[0][0];
#pragma unroll
  for (int k = 0; k < NK; ++k) {
    float w = e[k] * inv;  // w >= ~1e-6 -> normal, mantissa packing safe
    flat[t * NK + k] = bfl((fbits(w) & 0xFFFFFF00u) | (fbits(a[k]) & 0xFFu));
  }
  __syncthreads();
  float* dst = wpk + ((size_t)tensor * ROWS + blockRow0) * NK;
#pragma unroll
  for (int i = 0; i < NK; ++i) dst[t + i * BLK] = flat[t + i * BLK];
}

// Kernel B: wave-per-row gather + squared-diff partial per block.
__global__ __launch_bounds__(1024) void gather_kernel(
    const float* __restrict__ v_s, const float* __restrict__ v_t,
    const float* __restrict__ wpk, float* __restrict__ partial) {
  const int t = threadIdx.x, wv = t >> 6, l = t & 63;
  int row = blockIdx.x * RPB_B + wv;
  row = __builtin_amdgcn_readfirstlane(row);  // force SGPR: scalar w loads
  const int bh = row / Pp;
  const float* vsb = v_s + (size_t)bh * (Pp * Dd) + l;
  const float* vtb = v_t + (size_t)bh * (Pp * Dd) + l;
  const float* w0 = wpk + (size_t)row * NK;
  const float* w1 = wpk + ((size_t)ROWS + row) * NK;

  float acc = 0.f;
#pragma unroll
  for (int k = 0; k < NK; ++k) {
    float w = w0[k];
    int idx = (int)(fbits(w) & 0xFFu);
    acc = fmaf(w, vsb[idx * Dd], acc);
  }
#pragma unroll
  for (int k = 0; k < NK; ++k) {
    float w = w1[k];
    int idx = (int)(fbits(w) & 0xFFu);
    acc = fmaf(-w, vtb[idx * Dd], acc);
  }
  float sq = acc * acc;
#pragma unroll
  for (int off = 32; off > 0; off >>= 1) sq += __shfl_xor(sq, off, 64);

  __shared__ float red[RPB_B];
  if (l == 0) red[wv] = sq;
  __syncthreads();
  if (t == 0) {
    float tot = 0.f;
#pragma unroll
    for (int i = 0; i < RPB_B; ++i) tot += red[i];
    partial[blockIdx.x] = tot;
  }
}

// Kernel C: single-block final reduction.
__global__ __launch_bounds__(1024) void reduce_kernel(
    const float* __restrict__ partial, float* __restrict__ out) {
  const int t = threadIdx.x, wv = t >> 6, l = t & 63;
  float s = 0.f;
  for (int i = t; i < NB_B; i += 1024) s += partial[i];
#pragma unroll
  for (int off = 32; off > 0; off >>= 1) s += __shfl_xor(s, off, 64);
  __shared__ float red[16];
  if (l == 0) red[wv] = s;
  __syncthreads();
  if (t == 0) {
    float tot = 0.f;
#pragma unroll
    for (int i = 0; i < 16; ++i) tot += red[i];
    out[0] = tot * INV_N;
  }
}

extern "C" void kernel_launch(void* const* d_in, const int* in_sizes, int n_in,
                              void* d_out, int out_size, void* d_ws,
                              size_t ws_size, hipStream_t stream) {
  const float* att_s = (const float*)d_in[0];
  const float* att_t = (const float*)d_in[1];
  const float* v_s = (const float*)d_in[2];
  const float* v_t = (const float*)d_in[3];
  float* out = (float*)d_out;

  float* wpk = (float*)d_ws;                       // 2*ROWS*NK floats = 12.1 MB
  float* partial = wpk + (size_t)2 * ROWS * NK;    // + NB_B floats

  select_kernel<<<2 * NBLK, BLK, 0, stream>>>(att_s, att_t, wpk);
  gather_kernel<<<NB_B, 1024, 0, stream>>>(v_s, v_t, wpk, partial);
  reduce_kernel<<<1, 1024, 0, stream>>>(partial, out);
}